// Round 5
// baseline (194.759 us; speedup 1.0000x reference)
//
#include <hip/hip_runtime.h>
#include <hip/hip_bf16.h>
#include <hip/hip_fp8.h>
#include <cstdint>
#include <cstddef>

// Problem constants (x = (8192, 768) fp32)
#define GN 8192
#define GD 768           // elements per row; fp8 => 768 bytes per row
#define NB 64            // 128-row blocks
#define NTILE 2080       // NB*(NB+1)/2 triangular tiles
#define KI 6             // 768 / 128 K-iterations

typedef __attribute__((ext_vector_type(4))) int i32x4;
typedef __attribute__((ext_vector_type(8))) int i32x8;
typedef __attribute__((ext_vector_type(4))) float f32x4;

typedef __attribute__((address_space(1))) const unsigned int gu32;
typedef __attribute__((address_space(3))) unsigned int lu32;

__device__ __forceinline__ void gl2lds16(const void* g, void* l) {
    // async global->LDS, 16B per lane; LDS dest is wave-uniform base + lane*16
    __builtin_amdgcn_global_load_lds((gu32*)g, (lu32*)l, 16, 0, 0);
}

// ---------------- Kernel 1: fp8 e4m3 quantize + row sum-of-squares of the
// DEQUANTIZED values (makes sim structurally exact for the quantized data:
// sim_ij = -||x^_i - x^_j||^2 - 100*diag, so diagonal = -100 +- 1e-4) --------
__global__ __launch_bounds__(256) void prep_kernel(const float* __restrict__ x,
                                                   unsigned char* __restrict__ xq,
                                                   float* __restrict__ sq,
                                                   float* __restrict__ out) {
    if (blockIdx.x == 0 && threadIdx.x == 0) out[0] = 0.f;  // for combine's atomics
    const int w = threadIdx.x >> 6, lane = threadIdx.x & 63;
    const int row = blockIdx.x * 4 + w;
    const float4* xr = (const float4*)(x + (size_t)row * GD);
    unsigned int* xqr = (unsigned int*)(xq + (size_t)row * GD);
    float s = 0.f;
#pragma unroll
    for (int i = 0; i < 3; ++i) {
        float4 v = xr[lane + 64 * i];
        __hip_fp8_e4m3 q0(v.x), q1(v.y), q2(v.z), q3(v.w);
        float d0 = (float)q0, d1 = (float)q1, d2 = (float)q2, d3 = (float)q3;
        s += d0 * d0 + d1 * d1 + d2 * d2 + d3 * d3;
        xqr[lane + 64 * i] = (unsigned int)q0.__x | ((unsigned int)q1.__x << 8) |
                             ((unsigned int)q2.__x << 16) | ((unsigned int)q3.__x << 24);
    }
#pragma unroll
    for (int off = 1; off < 64; off <<= 1) s += __shfl_xor(s, off);
    if (lane == 0) sq[row] = s;
}

// ------- Kernel 2: symmetric triangular tile GEMM (MX-fp8, scale=1) + entropy -------
// One 128x128 tile (I,J), J<=I, per WG. 4 waves stacked in M (32 rows x 128 cols).
// mfma_scale_f32_16x16x128_f8f6f4: A[m=lane&15][k=(lane>>4)*32+j], j in [0,32);
// C/D: col=lane&15, row=(lane>>4)*4+reg (same as 16x16x32 bf16 -> epilogue reused).
// LDS: row = 128 B = 8 x 16B units; unit swizzle phys = (u + row) & 7 -> bank-floor
// ds_read_b128; staging decode inverts the swizzle (global side is free to permute).
__global__ __launch_bounds__(256, 2) void sym_gemm_entropy(
    const unsigned char* __restrict__ xq, const float* __restrict__ sq,
    const float* __restrict__ taup, float* __restrict__ pm,
    float* __restrict__ ps, float* __restrict__ pt) {
    __shared__ __align__(16) char lds[65536];  // [A0 16K][B0 16K][A1 16K][B1 16K]
    float (*tmrg)[4][3] = (float (*)[4][3])lds;  // aliased; used only after K-loop

    const int tid = threadIdx.x;
    const int lane = tid & 63;
    const int w = tid >> 6;
    const int quad = lane >> 4, cl = lane & 15;

    const int b = blockIdx.x;
    int I = (int)((sqrtf(8.0f * (float)b + 1.0f) - 1.0f) * 0.5f);
    while ((I + 1) * (I + 2) / 2 <= b) ++I;
    while (I * (I + 1) / 2 > b) --I;
    const int J = b - I * (I + 1) / 2;
    const int row_base = I * 128;
    const int col_base = J * 128;
    const float tau = *taup;

    // staging decode: thread t, load n stages LDS slot (t + 256n): row r = (t>>3)+32n,
    // phys unit p = t&7, logical unit u = (p - r) & 7 (constant across n since 32n%8==0)
    const int r0 = tid >> 3;
    const int uu = ((tid & 7) - r0) & 7;
    const unsigned char* gA = xq + (size_t)(row_base + r0) * GD + uu * 16;
    const unsigned char* gB = xq + (size_t)(col_base + r0) * GD + uu * 16;

    // fragment LDS offsets: row m, logical units {2q, 2q+1} -> phys (u+m)&7
    int offA[2][2], offB[8][2];
#pragma unroll
    for (int ti = 0; ti < 2; ++ti) {
        int m = w * 32 + ti * 16 + cl;
        offA[ti][0] = m * 128 + (((2 * quad) + m) & 7) * 16;
        offA[ti][1] = m * 128 + (((2 * quad + 1) + m) & 7) * 16;
    }
#pragma unroll
    for (int tj = 0; tj < 8; ++tj) {
        int n = tj * 16 + cl;
        offB[tj][0] = n * 128 + (((2 * quad) + n) & 7) * 16;
        offB[tj][1] = n * 128 + (((2 * quad + 1) + n) & 7) * 16;
    }

    f32x4 acc[2][8];
#pragma unroll
    for (int i = 0; i < 2; ++i)
#pragma unroll
        for (int j = 0; j < 8; ++j) acc[i][j] = (f32x4){0.f, 0.f, 0.f, 0.f};

    // prologue: stage k=0 into buffer 0 (A: 4 loads, B: 4 loads per thread)
#pragma unroll
    for (int n = 0; n < 4; ++n) {
        gl2lds16(gA + (size_t)n * 32 * GD, lds + tid * 16 + n * 4096);
        gl2lds16(gB + (size_t)n * 32 * GD, lds + 16384 + tid * 16 + n * 4096);
    }

#pragma unroll
    for (int kk = 0; kk < KI; ++kk) {
        __syncthreads();  // buf[kk&1] staged; prior buf's ds_reads done

        const char* Ab = lds + (kk & 1) * 32768;
        const char* Bb = Ab + 16384;
        i32x8 af[2], bfv[8];
#pragma unroll
        for (int ti = 0; ti < 2; ++ti) {
            i32x4 lo = *(const i32x4*)(Ab + offA[ti][0]);
            i32x4 hi = *(const i32x4*)(Ab + offA[ti][1]);
            af[ti] = __builtin_shufflevector(lo, hi, 0, 1, 2, 3, 4, 5, 6, 7);
        }
#pragma unroll
        for (int tj = 0; tj < 8; ++tj) {
            i32x4 lo = *(const i32x4*)(Bb + offB[tj][0]);
            i32x4 hi = *(const i32x4*)(Bb + offB[tj][1]);
            bfv[tj] = __builtin_shufflevector(lo, hi, 0, 1, 2, 3, 4, 5, 6, 7);
        }

        // prefetch k+1 into the other buffer; drains only at the next barrier
        if (kk + 1 < KI) {
            char* An = lds + ((kk + 1) & 1) * 32768;
            const int ko = (kk + 1) * 128;  // byte offset along K
#pragma unroll
            for (int n = 0; n < 4; ++n) {
                gl2lds16(gA + (size_t)n * 32 * GD + ko, An + tid * 16 + n * 4096);
                gl2lds16(gB + (size_t)n * 32 * GD + ko, An + 16384 + tid * 16 + n * 4096);
            }
        }

#pragma unroll
        for (int ti = 0; ti < 2; ++ti)
#pragma unroll
            for (int tj = 0; tj < 8; ++tj)
                acc[ti][tj] = __builtin_amdgcn_mfma_scale_f32_16x16x128_f8f6f4(
                    af[ti], bfv[tj], acc[ti][tj], 0, 0,  // cbsz=fp8, blgp=fp8
                    0, 0x7F7F7F7F,                       // opsel_a, scale_a = 1.0 (e8m0 127)
                    0, 0x7F7F7F7F);                      // opsel_b, scale_b = 1.0
    }

    // per-lane metadata
    float sqr[8];
    int rowg[8];
#pragma unroll
    for (int ti = 0; ti < 2; ++ti)
#pragma unroll
        for (int rg = 0; rg < 4; ++rg) {
            int r = row_base + w * 32 + ti * 16 + quad * 4 + rg;
            rowg[ti * 4 + rg] = r;
            sqr[ti * 4 + rg] = sq[r];
        }
    float sqc[8];
    int colg[8];
#pragma unroll
    for (int tj = 0; tj < 8; ++tj) {
        int c = col_base + tj * 16 + cl;
        colg[tj] = c;
        sqc[tj] = sq[c];
    }

    // ---- direct pass: one (m,S,T) per row of block I over J's 128 cols ----
#pragma unroll
    for (int ti = 0; ti < 2; ++ti)
#pragma unroll
        for (int rg = 0; rg < 4; ++rg) {
            const int idx = ti * 4 + rg;
            float vv[8];
            float mloc = -1e30f;
#pragma unroll
            for (int tj = 0; tj < 8; ++tj) {
                float pen = (rowg[idx] == colg[tj]) ? 100.f : 0.f;
                float v = tau * (2.f * acc[ti][tj][rg] - sqr[idx] - sqc[tj] - pen);
                vv[tj] = v;
                mloc = fmaxf(mloc, v);
            }
#pragma unroll
            for (int mk = 1; mk < 16; mk <<= 1) mloc = fmaxf(mloc, __shfl_xor(mloc, mk));
            float s = 0.f, t = 0.f;
#pragma unroll
            for (int tj = 0; tj < 8; ++tj) {
                float d = vv[tj] - mloc;
                float e = __expf(d);
                s += e;
                t += e * d;
            }
#pragma unroll
            for (int mk = 1; mk < 16; mk <<= 1) {
                s += __shfl_xor(s, mk);
                t += __shfl_xor(t, mk);
            }
            if (cl == 0) {
                int r = rowg[idx];
                pm[(size_t)J * GN + r] = mloc;
                ps[(size_t)J * GN + r] = s;
                pt[(size_t)J * GN + r] = t;
            }
        }

    // ---- transposed pass (off-diagonal tiles): rows of block J over I's rows ----
    if (I != J) {  // block-uniform branch
#pragma unroll
        for (int tj = 0; tj < 8; ++tj) {
            float vv[8];
            float mloc = -1e30f;
#pragma unroll
            for (int ti = 0; ti < 2; ++ti)
#pragma unroll
                for (int rg = 0; rg < 4; ++rg) {
                    float v = tau * (2.f * acc[ti][tj][rg] - sqr[ti * 4 + rg] - sqc[tj]);
                    vv[ti * 4 + rg] = v;
                    mloc = fmaxf(mloc, v);
                }
            mloc = fmaxf(mloc, __shfl_xor(mloc, 16));
            mloc = fmaxf(mloc, __shfl_xor(mloc, 32));
            float s = 0.f, t = 0.f;
#pragma unroll
            for (int k = 0; k < 8; ++k) {
                float d = vv[k] - mloc;
                float e = __expf(d);
                s += e;
                t += e * d;
            }
            s += __shfl_xor(s, 16);
            t += __shfl_xor(t, 16);
            s += __shfl_xor(s, 32);
            t += __shfl_xor(t, 32);
            if (quad == 0) {
                int c = tj * 16 + cl;
                tmrg[c][w][0] = mloc;
                tmrg[c][w][1] = s;
                tmrg[c][w][2] = t;
            }
        }
        __syncthreads();
        if (tid < 128) {
            float m = tmrg[tid][0][0], S = tmrg[tid][0][1], T = tmrg[tid][0][2];
#pragma unroll
            for (int ww = 1; ww < 4; ++ww) {
                float mc = tmrg[tid][ww][0], Sc = tmrg[tid][ww][1], Tc = tmrg[tid][ww][2];
                float mn = fmaxf(m, mc);
                float ea = __expf(m - mn), eb = __expf(mc - mn);
                T = (T + (m - mn) * S) * ea + (Tc + (mc - mn) * Sc) * eb;
                S = S * ea + Sc * eb;
                m = mn;
            }
            int c = col_base + tid;
            pm[(size_t)I * GN + c] = m;
            ps[(size_t)I * GN + c] = S;
            pt[(size_t)I * GN + c] = T;
        }
    }
}

// ---------------- Kernel 3: combine 64 slots -> row entropy -> atomic scalar ----------------
__global__ __launch_bounds__(256) void combine(const float* __restrict__ pm,
                                               const float* __restrict__ ps,
                                               const float* __restrict__ pt,
                                               const float* __restrict__ coefp,
                                               float* __restrict__ out) {
    const int row = blockIdx.x * 256 + threadIdx.x;
    float m = -1e30f, S = 0.f, T = 0.f;
    for (int c = 0; c < NB; ++c) {
        float mc = pm[(size_t)c * GN + row];
        float Sc = ps[(size_t)c * GN + row];
        float Tc = pt[(size_t)c * GN + row];
        float mn = fmaxf(m, mc);
        float ea = __expf(m - mn), eb = __expf(mc - mn);
        T = (T + (m - mn) * S) * ea + (Tc + (mc - mn) * Sc) * eb;
        S = S * ea + Sc * eb;
        m = mn;
    }
    float ent = __logf(S) - T / S;
#pragma unroll
    for (int off = 1; off < 64; off <<= 1) ent += __shfl_xor(ent, off);
    __shared__ float ls[4];
    if ((threadIdx.x & 63) == 0) ls[threadIdx.x >> 6] = ent;
    __syncthreads();
    if (threadIdx.x == 0)
        atomicAdd(out, (ls[0] + ls[1] + ls[2] + ls[3]) * coefp[0] * (1.0f / (float)GN));
}

extern "C" void kernel_launch(void* const* d_in, const int* in_sizes, int n_in,
                              void* d_out, int out_size, void* d_ws, size_t ws_size,
                              hipStream_t stream) {
    const float* x = (const float*)d_in[0];      // 8192*768 fp32
    const float* coefp = (const float*)d_in[1];  // scalar
    const float* taup = (const float*)d_in[2];   // scalar
    float* out = (float*)d_out;

    char* ws = (char*)d_ws;
    unsigned char* xq = (unsigned char*)ws;              // 6,291,456 B (fp8)
    float* sq = (float*)(ws + 6291456);                  // 32,768 B
    float* pm = (float*)(ws + 6324224);                  // 2,097,152 B
    float* ps = (float*)(ws + 6324224 + 2097152);        // 2,097,152 B
    float* pt = (float*)(ws + 6324224 + 2 * 2097152);    // 2,097,152 B

    prep_kernel<<<GN / 4, 256, 0, stream>>>(x, xq, sq, out);
    sym_gemm_entropy<<<NTILE, 256, 0, stream>>>(xq, sq, taup, pm, ps, pt);
    combine<<<GN / 256, 256, 0, stream>>>(pm, ps, pt, coefp, out);
}

// Round 6
// 184.722 us; speedup vs baseline: 1.0543x; 1.0543x over previous
//
#include <hip/hip_runtime.h>
#include <hip/hip_bf16.h>
#include <hip/hip_fp8.h>
#include <cstdint>
#include <cstddef>

// Problem constants (x = (8192, 768) fp32)
#define GN 8192
#define GD 768           // elements per row; fp8 => 768 bytes per row
#define NB 64            // 128-row blocks
#define NTILE 2080       // NB*(NB+1)/2 triangular tiles
#define KI 6             // 768 / 128 K-iterations

typedef __attribute__((ext_vector_type(4))) int i32x4;
typedef __attribute__((ext_vector_type(8))) int i32x8;
typedef __attribute__((ext_vector_type(4))) float f32x4;

typedef __attribute__((address_space(1))) const unsigned int gu32;
typedef __attribute__((address_space(3))) unsigned int lu32;

__device__ __forceinline__ void gl2lds16(const void* g, void* l) {
    // async global->LDS, 16B per lane; LDS dest is wave-uniform base + lane*16
    __builtin_amdgcn_global_load_lds((gu32*)g, (lu32*)l, 16, 0, 0);
}

__device__ __forceinline__ i32x8 ldfrag(const char* base, int off0, int off1) {
    i32x4 lo = *(const i32x4*)(base + off0);
    i32x4 hi = *(const i32x4*)(base + off1);
    return __builtin_shufflevector(lo, hi, 0, 1, 2, 3, 4, 5, 6, 7);
}

// ---------------- Kernel 1: fp8 e4m3 quantize + row sum-of-squares of the
// DEQUANTIZED values (makes sim structurally exact for the quantized data:
// sim_ij = -||x^_i - x^_j||^2 - 100*diag, so diagonal = -100 +- 1e-4) --------
__global__ __launch_bounds__(256) void prep_kernel(const float* __restrict__ x,
                                                   unsigned char* __restrict__ xq,
                                                   float* __restrict__ sq,
                                                   float* __restrict__ out) {
    if (blockIdx.x == 0 && threadIdx.x == 0) out[0] = 0.f;  // for combine's atomics
    const int w = threadIdx.x >> 6, lane = threadIdx.x & 63;
    const int row = blockIdx.x * 4 + w;
    const float4* xr = (const float4*)(x + (size_t)row * GD);
    unsigned int* xqr = (unsigned int*)(xq + (size_t)row * GD);
    float s = 0.f;
#pragma unroll
    for (int i = 0; i < 3; ++i) {
        float4 v = xr[lane + 64 * i];
        __hip_fp8_e4m3 q0(v.x), q1(v.y), q2(v.z), q3(v.w);
        float d0 = (float)q0, d1 = (float)q1, d2 = (float)q2, d3 = (float)q3;
        s += d0 * d0 + d1 * d1 + d2 * d2 + d3 * d3;
        xqr[lane + 64 * i] = (unsigned int)q0.__x | ((unsigned int)q1.__x << 8) |
                             ((unsigned int)q2.__x << 16) | ((unsigned int)q3.__x << 24);
    }
#pragma unroll
    for (int off = 1; off < 64; off <<= 1) s += __shfl_xor(s, off);
    if (lane == 0) sq[row] = s;
}

// ------- Kernel 2: symmetric triangular tile GEMM (MX-fp8, scale=1) + entropy -------
// One 128x128 tile (I,J), J<=I, per WG. 4 waves stacked in M (32 rows x 128 cols).
// mfma_scale_f32_16x16x128_f8f6f4: A[m=lane&15][k=(lane>>4)*32+j], j in [0,32);
// C/D: col=lane&15, row=(lane>>4)*4+reg (verified by R5's pass).
// Register-pressure discipline (R5 spilled 165 MB to scratch): at most 5 B
// fragments live (depth-4 rotation), no launch_bounds wave cap.
__global__ __launch_bounds__(256) void sym_gemm_entropy(
    const unsigned char* __restrict__ xq, const float* __restrict__ sq,
    const float* __restrict__ taup, float* __restrict__ pm,
    float* __restrict__ ps, float* __restrict__ pt) {
    __shared__ __align__(16) char lds[65536];  // [A0 16K][B0 16K][A1 16K][B1 16K]
    float (*tmrg)[4][3] = (float (*)[4][3])lds;  // aliased; used only after K-loop

    const int tid = threadIdx.x;
    const int lane = tid & 63;
    const int w = tid >> 6;
    const int quad = lane >> 4, cl = lane & 15;

    const int b = blockIdx.x;
    int I = (int)((sqrtf(8.0f * (float)b + 1.0f) - 1.0f) * 0.5f);
    while ((I + 1) * (I + 2) / 2 <= b) ++I;
    while (I * (I + 1) / 2 > b) --I;
    const int J = b - I * (I + 1) / 2;
    const int row_base = I * 128;
    const int col_base = J * 128;
    const float tau = *taup;

    // staging decode: thread t, load n stages LDS slot (t + 256n): row r = (t>>3)+32n,
    // phys unit p = t&7, logical unit u = (p - r) & 7 (constant across n since 32n%8==0)
    const int r0 = tid >> 3;
    const int uu = ((tid & 7) - r0) & 7;
    const unsigned char* gA = xq + (size_t)(row_base + r0) * GD + uu * 16;
    const unsigned char* gB = xq + (size_t)(col_base + r0) * GD + uu * 16;

    // fragment LDS offsets: row m, logical units {2q, 2q+1} -> phys (u+m)&7
    int offA[2][2], offB[8][2];
#pragma unroll
    for (int ti = 0; ti < 2; ++ti) {
        int m = w * 32 + ti * 16 + cl;
        offA[ti][0] = m * 128 + (((2 * quad) + m) & 7) * 16;
        offA[ti][1] = m * 128 + (((2 * quad + 1) + m) & 7) * 16;
    }
#pragma unroll
    for (int tj = 0; tj < 8; ++tj) {
        int n = tj * 16 + cl;
        offB[tj][0] = n * 128 + (((2 * quad) + n) & 7) * 16;
        offB[tj][1] = n * 128 + (((2 * quad + 1) + n) & 7) * 16;
    }

    f32x4 acc[2][8];
#pragma unroll
    for (int i = 0; i < 2; ++i)
#pragma unroll
        for (int j = 0; j < 8; ++j) acc[i][j] = (f32x4){0.f, 0.f, 0.f, 0.f};

    // prologue: stage k=0 into buffer 0 (A: 4 loads, B: 4 loads per thread)
#pragma unroll
    for (int n = 0; n < 4; ++n) {
        gl2lds16(gA + (size_t)n * 32 * GD, lds + tid * 16 + n * 4096);
        gl2lds16(gB + (size_t)n * 32 * GD, lds + 16384 + tid * 16 + n * 4096);
    }

#pragma unroll
    for (int kk = 0; kk < KI; ++kk) {
        __syncthreads();  // buf[kk&1] staged; prior buf's ds_reads done

        const char* Ab = lds + (kk & 1) * 32768;
        const char* Bb = Ab + 16384;

        // A fragments (2 live) + first half of B (4 live)
        i32x8 af0 = ldfrag(Ab, offA[0][0], offA[0][1]);
        i32x8 af1 = ldfrag(Ab, offA[1][0], offA[1][1]);
        i32x8 bf[4];
#pragma unroll
        for (int j = 0; j < 4; ++j) bf[j] = ldfrag(Bb, offB[j][0], offB[j][1]);

        // prefetch k+1 into the other buffer; drains only at the next barrier
        if (kk + 1 < KI) {
            char* An = lds + ((kk + 1) & 1) * 32768;
            const int ko = (kk + 1) * 128;  // byte offset along K
#pragma unroll
            for (int n = 0; n < 4; ++n) {
                gl2lds16(gA + (size_t)n * 32 * GD + ko, An + tid * 16 + n * 4096);
                gl2lds16(gB + (size_t)n * 32 * GD + ko, An + 16384 + tid * 16 + n * 4096);
            }
        }

        // depth-4 rotating MFMA loop: load bf[tj+4] before consuming bf[tj]
#pragma unroll
        for (int tj = 0; tj < 8; ++tj) {
            i32x8 cur = bf[tj & 3];
            if (tj + 4 < 8) bf[tj & 3] = ldfrag(Bb, offB[tj + 4][0], offB[tj + 4][1]);
            acc[0][tj] = __builtin_amdgcn_mfma_scale_f32_16x16x128_f8f6f4(
                af0, cur, acc[0][tj], 0, 0, 0, 0x7F7F7F7F, 0, 0x7F7F7F7F);
            acc[1][tj] = __builtin_amdgcn_mfma_scale_f32_16x16x128_f8f6f4(
                af1, cur, acc[1][tj], 0, 0, 0, 0x7F7F7F7F, 0, 0x7F7F7F7F);
        }
    }

    // per-lane metadata
    float sqr[8];
    int rowg[8];
#pragma unroll
    for (int ti = 0; ti < 2; ++ti)
#pragma unroll
        for (int rg = 0; rg < 4; ++rg) {
            int r = row_base + w * 32 + ti * 16 + quad * 4 + rg;
            rowg[ti * 4 + rg] = r;
            sqr[ti * 4 + rg] = sq[r];
        }
    float sqc[8];
    int colg[8];
#pragma unroll
    for (int tj = 0; tj < 8; ++tj) {
        int c = col_base + tj * 16 + cl;
        colg[tj] = c;
        sqc[tj] = sq[c];
    }

    // ---- direct pass: one (m,S,T) per row of block I over J's 128 cols ----
#pragma unroll
    for (int ti = 0; ti < 2; ++ti)
#pragma unroll
        for (int rg = 0; rg < 4; ++rg) {
            const int idx = ti * 4 + rg;
            float vv[8];
            float mloc = -1e30f;
#pragma unroll
            for (int tj = 0; tj < 8; ++tj) {
                float pen = (rowg[idx] == colg[tj]) ? 100.f : 0.f;
                float v = tau * (2.f * acc[ti][tj][rg] - sqr[idx] - sqc[tj] - pen);
                vv[tj] = v;
                mloc = fmaxf(mloc, v);
            }
#pragma unroll
            for (int mk = 1; mk < 16; mk <<= 1) mloc = fmaxf(mloc, __shfl_xor(mloc, mk));
            float s = 0.f, t = 0.f;
#pragma unroll
            for (int tj = 0; tj < 8; ++tj) {
                float d = vv[tj] - mloc;
                float e = __expf(d);
                s += e;
                t += e * d;
            }
#pragma unroll
            for (int mk = 1; mk < 16; mk <<= 1) {
                s += __shfl_xor(s, mk);
                t += __shfl_xor(t, mk);
            }
            if (cl == 0) {
                int r = rowg[idx];
                pm[(size_t)J * GN + r] = mloc;
                ps[(size_t)J * GN + r] = s;
                pt[(size_t)J * GN + r] = t;
            }
        }

    // ---- transposed pass (off-diagonal tiles): rows of block J over I's rows ----
    if (I != J) {  // block-uniform branch
#pragma unroll
        for (int tj = 0; tj < 8; ++tj) {
            float vv[8];
            float mloc = -1e30f;
#pragma unroll
            for (int ti = 0; ti < 2; ++ti)
#pragma unroll
                for (int rg = 0; rg < 4; ++rg) {
                    float v = tau * (2.f * acc[ti][tj][rg] - sqr[ti * 4 + rg] - sqc[tj]);
                    vv[ti * 4 + rg] = v;
                    mloc = fmaxf(mloc, v);
                }
            mloc = fmaxf(mloc, __shfl_xor(mloc, 16));
            mloc = fmaxf(mloc, __shfl_xor(mloc, 32));
            float s = 0.f, t = 0.f;
#pragma unroll
            for (int k = 0; k < 8; ++k) {
                float d = vv[k] - mloc;
                float e = __expf(d);
                s += e;
                t += e * d;
            }
            s += __shfl_xor(s, 16);
            t += __shfl_xor(t, 16);
            s += __shfl_xor(s, 32);
            t += __shfl_xor(t, 32);
            if (quad == 0) {
                int c = tj * 16 + cl;
                tmrg[c][w][0] = mloc;
                tmrg[c][w][1] = s;
                tmrg[c][w][2] = t;
            }
        }
        __syncthreads();
        if (tid < 128) {
            float m = tmrg[tid][0][0], S = tmrg[tid][0][1], T = tmrg[tid][0][2];
#pragma unroll
            for (int ww = 1; ww < 4; ++ww) {
                float mc = tmrg[tid][ww][0], Sc = tmrg[tid][ww][1], Tc = tmrg[tid][ww][2];
                float mn = fmaxf(m, mc);
                float ea = __expf(m - mn), eb = __expf(mc - mn);
                T = (T + (m - mn) * S) * ea + (Tc + (mc - mn) * Sc) * eb;
                S = S * ea + Sc * eb;
                m = mn;
            }
            int c = col_base + tid;
            pm[(size_t)I * GN + c] = m;
            ps[(size_t)I * GN + c] = S;
            pt[(size_t)I * GN + c] = T;
        }
    }
}

// ---------------- Kernel 3: combine 64 slots -> row entropy -> atomic scalar ----------------
__global__ __launch_bounds__(256) void combine(const float* __restrict__ pm,
                                               const float* __restrict__ ps,
                                               const float* __restrict__ pt,
                                               const float* __restrict__ coefp,
                                               float* __restrict__ out) {
    const int row = blockIdx.x * 256 + threadIdx.x;
    float m = -1e30f, S = 0.f, T = 0.f;
    for (int c = 0; c < NB; ++c) {
        float mc = pm[(size_t)c * GN + row];
        float Sc = ps[(size_t)c * GN + row];
        float Tc = pt[(size_t)c * GN + row];
        float mn = fmaxf(m, mc);
        float ea = __expf(m - mn), eb = __expf(mc - mn);
        T = (T + (m - mn) * S) * ea + (Tc + (mc - mn) * Sc) * eb;
        S = S * ea + Sc * eb;
        m = mn;
    }
    float ent = __logf(S) - T / S;
#pragma unroll
    for (int off = 1; off < 64; off <<= 1) ent += __shfl_xor(ent, off);
    __shared__ float ls[4];
    if ((threadIdx.x & 63) == 0) ls[threadIdx.x >> 6] = ent;
    __syncthreads();
    if (threadIdx.x == 0)
        atomicAdd(out, (ls[0] + ls[1] + ls[2] + ls[3]) * coefp[0] * (1.0f / (float)GN));
}

extern "C" void kernel_launch(void* const* d_in, const int* in_sizes, int n_in,
                              void* d_out, int out_size, void* d_ws, size_t ws_size,
                              hipStream_t stream) {
    const float* x = (const float*)d_in[0];      // 8192*768 fp32
    const float* coefp = (const float*)d_in[1];  // scalar
    const float* taup = (const float*)d_in[2];   // scalar
    float* out = (float*)d_out;

    char* ws = (char*)d_ws;
    unsigned char* xq = (unsigned char*)ws;              // 6,291,456 B (fp8)
    float* sq = (float*)(ws + 6291456);                  // 32,768 B
    float* pm = (float*)(ws + 6324224);                  // 2,097,152 B
    float* ps = (float*)(ws + 6324224 + 2097152);        // 2,097,152 B
    float* pt = (float*)(ws + 6324224 + 2 * 2097152);    // 2,097,152 B

    prep_kernel<<<GN / 4, 256, 0, stream>>>(x, xq, sq, out);
    sym_gemm_entropy<<<NTILE, 256, 0, stream>>>(xq, sq, taup, pm, ps, pt);
    combine<<<GN / 256, 256, 0, stream>>>(pm, ps, pt, coefp, out);
}